// Round 7
// baseline (589.033 us; speedup 1.0000x reference)
//
#include <hip/hip_runtime.h>
#include <hip/hip_bf16.h>
#include <cstddef>
#include <cstdint>

#define IN_DIM 256
#define HID 128
#define OUT_DIM 40

#define CHUNK 8192      // edges per binscatter block (private staging region)
#define BIN_SHIFT 10    // 1024 nodes per bin
#define BIN_SIZE 1024
#define MAXB 128        // >= NBINS+1
#define GSPLIT 8        // blocks per bin for hist/col kernels

typedef __attribute__((ext_vector_type(8))) short short8;
typedef __attribute__((ext_vector_type(4))) float f32x4;
typedef __attribute__((ext_vector_type(2))) float f32x2;

__device__ inline short f2bf(float f) {
    __hip_bfloat16 b = __float2bfloat16(f);   // RNE
    return __builtin_bit_cast(short, b);
}
__device__ inline float bf2f(unsigned short u) {
    unsigned int v = (unsigned int)u << 16;
    return __builtin_bit_cast(float, v);
}
// feature permutation for h1/x1 storage: slot p holds feature (p>>3) + 16*(p&7).
__device__ inline int permf(int p) { return (p >> 3) + 16 * (p & 7); }

// ---------------- CSR build: chunk-private counting sort by dst bin ----------------
// deg_out computed inline via global atomics (random, overlapped with LDS work).
__global__ __launch_bounds__(256) void k_binscatter(const int* __restrict__ src, const int* __restrict__ dst,
                                                    uint32_t* __restrict__ stD, int* __restrict__ bboD,
                                                    int* __restrict__ deg_out, int E, int NBINS) {
    __shared__ int hD[MAXB], cD[MAXB], sd[MAXB];
    int j = blockIdx.x, t = threadIdx.x;
    int base = j * CHUNK;
    int nE = min(CHUNK, E - base);
    int NB1 = NBINS + 1;
    for (int i = t; i < MAXB; i += 256) hD[i] = 0;
    __syncthreads();
    for (int i = t; i < nE; i += 256) {
        atomicAdd(&hD[dst[base + i] >> BIN_SHIFT], 1);
        atomicAdd(&deg_out[src[base + i]], 1);
    }
    __syncthreads();
    if (t < MAXB) sd[t] = hD[t];
    __syncthreads();
    for (int off = 1; off < MAXB; off <<= 1) {
        int x = 0;
        if (t < MAXB && t >= off) x = sd[t - off];
        __syncthreads();
        if (t < MAXB) sd[t] += x;
        __syncthreads();
    }
    if (t < MAXB) cD[t] = sd[t] - hD[t];
    if (t < NBINS) bboD[(size_t)j * NB1 + t] = sd[t] - hD[t];
    if (t == NBINS) bboD[(size_t)j * NB1 + NBINS] = nE;
    __syncthreads();
    for (int i = t; i < nE; i += 256) {
        int s = src[base + i], d = dst[base + i];
        int pD = atomicAdd(&cD[d >> BIN_SHIFT], 1);
        stD[(size_t)base + pD] = ((uint32_t)(d & (BIN_SIZE - 1)) << 17) | (uint32_t)s;
    }
}

// grid (NBINS, GSPLIT): per-(bin,g) partial histogram -> pph (no atomic merge)
__global__ __launch_bounds__(256) void k_hist(const uint32_t* __restrict__ stD, const int* __restrict__ bboD,
                                              int* __restrict__ pph, int nchunk, int NBINS) {
    __shared__ int hist[BIN_SIZE];
    int b = blockIdx.x, g = blockIdx.y, t = threadIdx.x;
    int wv = t >> 6, lane = t & 63;
    int NB1 = NBINS + 1;
    for (int i = t; i < BIN_SIZE; i += 256) hist[i] = 0;
    __syncthreads();
    for (int j = g * 4 + wv; j < nchunk; j += GSPLIT * 4) {
        int s = bboD[(size_t)j * NB1 + b], e = bboD[(size_t)j * NB1 + b + 1];
        const uint32_t* seg = stD + (size_t)j * CHUNK;
        for (int i = s + lane; i < e; i += 64)
            atomicAdd(&hist[seg[i] >> 17], 1);
    }
    __syncthreads();
    int base = ((b * GSPLIT + g) << BIN_SHIFT);
    for (int i = t; i < BIN_SIZE; i += 256)
        pph[base + i] = hist[i];
}

// exclusive scan; deg computed by summing the GSPLIT pph planes; fused rs_in
__global__ __launch_bounds__(256) void k_scan1(const int* __restrict__ pph, int* __restrict__ out,
                                               int* __restrict__ bsum, float* __restrict__ rs_in, int n) {
    __shared__ int sd[256];
    int t = threadIdx.x, b = blockIdx.x;
    int base = b * 1024 + t * 4;
    int v[4] = {0, 0, 0, 0};
#pragma unroll
    for (int r = 0; r < 4; ++r) {
        int node = base + r;
        if (node < n) {
            int bb = node >> BIN_SHIFT, il = node & (BIN_SIZE - 1);
            int d = 0;
#pragma unroll
            for (int g = 0; g < GSPLIT; ++g)
                d += pph[((bb * GSPLIT + g) << BIN_SHIFT) + il];
            v[r] = d;
            rs_in[node] = rsqrtf((float)max(d, 1));
        }
    }
    int ts = v[0] + v[1] + v[2] + v[3];
    sd[t] = ts;
    __syncthreads();
    for (int off = 1; off < 256; off <<= 1) {
        int x = 0;
        if (t >= off) x = sd[t - off];
        __syncthreads();
        sd[t] += x;
        __syncthreads();
    }
    int excl = sd[t] - ts;
    if (base + 0 < n) out[base + 0] = excl;
    if (base + 1 < n) out[base + 1] = excl + v[0];
    if (base + 2 < n) out[base + 2] = excl + v[0] + v[1];
    if (base + 3 < n) out[base + 3] = excl + v[0] + v[1] + v[2];
    if (t == 255) bsum[b] = sd[255];
}

__global__ __launch_bounds__(1024) void k_scan2(int* __restrict__ bsum, int nb) {
    __shared__ int sd[1024];
    int t = threadIdx.x;
    int v = (t < nb) ? bsum[t] : 0;
    sd[t] = v;
    __syncthreads();
    for (int off = 1; off < 1024; off <<= 1) {
        int x = 0;
        if (t >= off) x = sd[t - off];
        __syncthreads();
        sd[t] += x;
        __syncthreads();
    }
    if (t < nb) bsum[t] = sd[t] - v;   // exclusive
}

// finalize row_ptr; fused rs_out + per-(bin,g) cursor starts (prefix over g of pph)
__global__ __launch_bounds__(256) void k_scan3(int* __restrict__ row_ptr, const int* __restrict__ bsum,
                                               const int* __restrict__ pph, int* __restrict__ curg,
                                               const int* __restrict__ deg_out, float* __restrict__ rs_out,
                                               int n, int E) {
    int i = blockIdx.x * 256 + threadIdx.x;
    if (i < n) {
        int v = row_ptr[i] + bsum[i >> 10];
        row_ptr[i] = v;
        rs_out[i] = rsqrtf((float)max(deg_out[i], 1));
        int bb = i >> BIN_SHIFT, il = i & (BIN_SIZE - 1);
        int run = v;
#pragma unroll
        for (int g = 0; g < GSPLIT; ++g) {
            int idx = ((bb * GSPLIT + g) << BIN_SHIFT) + il;
            curg[idx] = run;
            run += pph[idx];
        }
    }
    if (i == 0) row_ptr[n] = E;
}

// grid (NBINS, GSPLIT): scatter-only (cursor starts precomputed in curg)
__global__ __launch_bounds__(256) void k_col(const uint32_t* __restrict__ stD, const int* __restrict__ bboD,
                                             const int* __restrict__ curg, int* __restrict__ col,
                                             int nchunk, int NBINS) {
    __shared__ int cur[BIN_SIZE];
    int b = blockIdx.x, g = blockIdx.y, t = threadIdx.x;
    int wv = t >> 6, lane = t & 63;
    int NB1 = NBINS + 1;
    int cbase = ((b * GSPLIT + g) << BIN_SHIFT);
    for (int i = t; i < BIN_SIZE; i += 256) cur[i] = curg[cbase + i];
    __syncthreads();
    for (int j = g * 4 + wv; j < nchunk; j += GSPLIT * 4) {
        int s = bboD[(size_t)j * NB1 + b], e = bboD[(size_t)j * NB1 + b + 1];
        const uint32_t* seg = stD + (size_t)j * CHUNK;
        for (int i = s + lane; i < e; i += 64) {
            uint32_t v = seg[i];
            int pos = atomicAdd(&cur[v >> 17], 1);
            col[pos] = (int)(v & 0x1FFFFu);
        }
    }
}

// ---------------- W1 repack (once): fp32 [256][128] -> bf16 fragments [nt][ks][lane][8] ----------------
__global__ __launch_bounds__(256) void k_wrepack(const float* __restrict__ B, short* __restrict__ Wg) {
    int u = blockIdx.x * 256 + threadIdx.x;   // 8192 float4 units
    int k = u >> 5;                           // 0..255
    int n0 = (u & 31) * 4;
    float4 v = *(const float4*)(B + (size_t)k * HID + n0);
    int ks = k >> 5, quad = (k >> 3) & 3, j = k & 7;
    float vv[4] = {v.x, v.y, v.z, v.w};
#pragma unroll
    for (int e = 0; e < 4; ++e) {
        int n = n0 + e;
        int nt = n >> 4;
        int ln = (n & 15) | (quad << 4);
        Wg[(((nt * 8 + ks) * 64) + ln) * 8 + j] = f2bf(vv[e]);
    }
}

// ---------------- GEMM1 (bf16 MFMA): h1f = fp8((h @ W1) * rs_out[row]), permuted columns ----------------
__global__ __launch_bounds__(256) void k_gemm1(const float* __restrict__ A, const short* __restrict__ Wg,
                                               const float* __restrict__ rs_out, uint32_t* __restrict__ h1f, int M) {
    __shared__ short As[64 * 264];            // [row][k], k-pitch 264 (33 KB)
    int t = threadIdx.x;
    int lane = t & 63, wv = t >> 6;
    int block_row = blockIdx.x * 64;
#pragma unroll
    for (int i = 0; i < 16; ++i) {
        int u = t + i * 256;                  // 4096 float4 units
        int row = u >> 6, kq = (u & 63) * 4;
        int gr = block_row + row;
        float4 v = {0.f, 0.f, 0.f, 0.f};
        if (gr < M) v = *(const float4*)(A + (size_t)gr * IN_DIM + kq);
        short4 sv = {f2bf(v.x), f2bf(v.y), f2bf(v.z), f2bf(v.w)};
        *(short4*)&As[row * 264 + kq] = sv;
    }
    __syncthreads();
    f32x4 acc[8] = {};
    int arow = (wv * 16 + (lane & 15)) * 264 + (lane >> 4) * 8;
#pragma unroll
    for (int ks = 0; ks < 8; ++ks) {
        short8 a = *(short8*)&As[arow + ks * 32];
#pragma unroll
        for (int nt = 0; nt < 8; ++nt) {
            short8 b = *(const short8*)&Wg[(((nt * 8 + ks) * 64) + lane) * 8];
            acc[nt] = __builtin_amdgcn_mfma_f32_16x16x32_bf16(a, b, acc[nt], 0, 0, 0);
        }
    }
    int quad = lane >> 4, cl = lane & 15;
#pragma unroll
    for (int r = 0; r < 4; ++r) {
        int gr = block_row + wv * 16 + quad * 4 + r;
        if (gr >= M) continue;
        float sc = rs_out[gr];
        int d0 = __builtin_amdgcn_cvt_pk_fp8_f32(acc[0][r] * sc, acc[1][r] * sc, 0, false);
        d0 = __builtin_amdgcn_cvt_pk_fp8_f32(acc[2][r] * sc, acc[3][r] * sc, d0, true);
        int d1 = __builtin_amdgcn_cvt_pk_fp8_f32(acc[4][r] * sc, acc[5][r] * sc, 0, false);
        d1 = __builtin_amdgcn_cvt_pk_fp8_f32(acc[6][r] * sc, acc[7][r] * sc, d1, true);
        uint2 dd = make_uint2((uint32_t)d0, (uint32_t)d1);
        *(uint2*)((char*)h1f + (size_t)gr * 128 + cl * 8) = dd;
    }
}

// ---------------- SpMM1 (fp8, MLP): 8 lanes/edge x dwordx4; f32x2 packed accumulate ----------------
__global__ __launch_bounds__(256) void k_spmm1(const uint4* __restrict__ h1f4, const int* __restrict__ rp,
                                               const int* __restrict__ col, const float* __restrict__ rs_in,
                                               const float* __restrict__ b1, uint32_t* __restrict__ x1b, int n) {
    int w = (blockIdx.x * 256 + threadIdx.x) >> 6;
    int lane = threadIdx.x & 63;
    if (w >= n) return;
    int grp = lane >> 3, ql = lane & 7;
    int s = rp[w], e = rp[w + 1];
    f32x2 acc[8] = {};
    int i = s;
    while (i < e) {
        int cnt = min(64, e - i);
        int cl = (lane < cnt) ? lane : cnt - 1;
        int cidx = col[i + cl];
        int it = 0;
        for (; it + 16 <= cnt; it += 16) {       // mask-free full batches
            int cA = __shfl(cidx, it + grp, 64);
            int cB = __shfl(cidx, it + 8 + grp, 64);
            uint4 uA = h1f4[(size_t)cA * 8 + ql];
            uint4 uB = h1f4[(size_t)cB * 8 + ql];
            acc[0] += __builtin_amdgcn_cvt_pk_f32_fp8(uA.x, false);
            acc[1] += __builtin_amdgcn_cvt_pk_f32_fp8(uA.x, true);
            acc[2] += __builtin_amdgcn_cvt_pk_f32_fp8(uA.y, false);
            acc[3] += __builtin_amdgcn_cvt_pk_f32_fp8(uA.y, true);
            acc[4] += __builtin_amdgcn_cvt_pk_f32_fp8(uA.z, false);
            acc[5] += __builtin_amdgcn_cvt_pk_f32_fp8(uA.z, true);
            acc[6] += __builtin_amdgcn_cvt_pk_f32_fp8(uA.w, false);
            acc[7] += __builtin_amdgcn_cvt_pk_f32_fp8(uA.w, true);
            acc[0] += __builtin_amdgcn_cvt_pk_f32_fp8(uB.x, false);
            acc[1] += __builtin_amdgcn_cvt_pk_f32_fp8(uB.x, true);
            acc[2] += __builtin_amdgcn_cvt_pk_f32_fp8(uB.y, false);
            acc[3] += __builtin_amdgcn_cvt_pk_f32_fp8(uB.y, true);
            acc[4] += __builtin_amdgcn_cvt_pk_f32_fp8(uB.z, false);
            acc[5] += __builtin_amdgcn_cvt_pk_f32_fp8(uB.z, true);
            acc[6] += __builtin_amdgcn_cvt_pk_f32_fp8(uB.w, false);
            acc[7] += __builtin_amdgcn_cvt_pk_f32_fp8(uB.w, true);
        }
        if (it < cnt) {                           // masked tail (<=15 edges)
            int eA = it + grp, eB = it + 8 + grp;
            int cA = __shfl(cidx, (eA < cnt) ? eA : 0, 64);
            int cB = __shfl(cidx, (eB < cnt) ? eB : 0, 64);
            float mA = (eA < cnt) ? 1.f : 0.f;
            float mB = (eB < cnt) ? 1.f : 0.f;
            f32x2 vA = {mA, mA}, vB = {mB, mB};
            uint4 uA = h1f4[(size_t)cA * 8 + ql];
            uint4 uB = h1f4[(size_t)cB * 8 + ql];
            acc[0] += __builtin_amdgcn_cvt_pk_f32_fp8(uA.x, false) * vA;
            acc[1] += __builtin_amdgcn_cvt_pk_f32_fp8(uA.x, true) * vA;
            acc[2] += __builtin_amdgcn_cvt_pk_f32_fp8(uA.y, false) * vA;
            acc[3] += __builtin_amdgcn_cvt_pk_f32_fp8(uA.y, true) * vA;
            acc[4] += __builtin_amdgcn_cvt_pk_f32_fp8(uA.z, false) * vA;
            acc[5] += __builtin_amdgcn_cvt_pk_f32_fp8(uA.z, true) * vA;
            acc[6] += __builtin_amdgcn_cvt_pk_f32_fp8(uA.w, false) * vA;
            acc[7] += __builtin_amdgcn_cvt_pk_f32_fp8(uA.w, true) * vA;
            acc[0] += __builtin_amdgcn_cvt_pk_f32_fp8(uB.x, false) * vB;
            acc[1] += __builtin_amdgcn_cvt_pk_f32_fp8(uB.x, true) * vB;
            acc[2] += __builtin_amdgcn_cvt_pk_f32_fp8(uB.y, false) * vB;
            acc[3] += __builtin_amdgcn_cvt_pk_f32_fp8(uB.y, true) * vB;
            acc[4] += __builtin_amdgcn_cvt_pk_f32_fp8(uB.z, false) * vB;
            acc[5] += __builtin_amdgcn_cvt_pk_f32_fp8(uB.z, true) * vB;
            acc[6] += __builtin_amdgcn_cvt_pk_f32_fp8(uB.w, false) * vB;
            acc[7] += __builtin_amdgcn_cvt_pk_f32_fp8(uB.w, true) * vB;
        }
        i += cnt;
    }
#pragma unroll
    for (int j = 0; j < 8; ++j) {
        acc[j].x += __shfl_xor(acc[j].x, 8, 64);  acc[j].y += __shfl_xor(acc[j].y, 8, 64);
        acc[j].x += __shfl_xor(acc[j].x, 16, 64); acc[j].y += __shfl_xor(acc[j].y, 16, 64);
        acc[j].x += __shfl_xor(acc[j].x, 32, 64); acc[j].y += __shfl_xor(acc[j].y, 32, 64);
    }
    if (lane < 8) {
        float sc = rs_in[w];
        int base_slot = lane * 16;
        uint32_t o[8];
#pragma unroll
        for (int j = 0; j < 8; ++j) {
            float f0 = fmaxf(fmaf(acc[j].x, sc, b1[permf(base_slot + 2 * j)]), 0.f);
            float f1 = fmaxf(fmaf(acc[j].y, sc, b1[permf(base_slot + 2 * j + 1)]), 0.f);
            o[j] = (uint32_t)(unsigned short)f2bf(f0) | ((uint32_t)(unsigned short)f2bf(f1) << 16);
        }
        uint4* dst = (uint4*)(x1b + (size_t)w * 64 + lane * 8);
        dst[0] = make_uint4(o[0], o[1], o[2], o[3]);
        dst[1] = make_uint4(o[4], o[5], o[6], o[7]);
    }
}

// ---------------- GEMM2: h2f = fp8((x1 @ W2) * rs_out[row])  (x1 bf16, column-permuted) ----------------
__global__ __launch_bounds__(256) void k_gemm2(const uint32_t* __restrict__ A, const float* __restrict__ B,
                                               const float* __restrict__ rs_out, unsigned char* __restrict__ h2f,
                                               int M) {
    __shared__ float As[64 * 132];       // [row][k], k-pitch 132
    __shared__ float Wt[OUT_DIM * 132];  // [col][k], k permuted to match x1
    __shared__ unsigned char hs[64 * 40];
    int t = threadIdx.x;
    int base_row = blockIdx.x * 64;
    for (int i = 0; i < 20; ++i) {
        int flat = t + i * 256;          // 5120
        int q = flat / 40, c = flat - q * 40;
        Wt[c * 132 + q] = B[(size_t)permf(q) * OUT_DIM + c];
    }
#pragma unroll
    for (int i = 0; i < 16; ++i) {
        int u = t + i * 256;             // 4096 dword units (2 feats each)
        int row = u >> 6, kc = u & 63;
        int gr = base_row + row;
        uint32_t v = (gr < M) ? A[(size_t)gr * 64 + kc] : 0;
        As[row * 132 + kc * 2] = bf2f((unsigned short)v);
        As[row * 132 + kc * 2 + 1] = bf2f((unsigned short)(v >> 16));
    }
    __syncthreads();
    int cg = t & 7, rg = t >> 3;
    int c0 = cg * 5, r0 = rg * 2;
    float acc[2][5] = {};
    for (int k = 0; k < HID; k += 4) {
        float4 a0 = *(const float4*)&As[r0 * 132 + k];
        float4 a1 = *(const float4*)&As[(r0 + 1) * 132 + k];
#pragma unroll
        for (int j = 0; j < 5; ++j) {
            float4 wv = *(const float4*)&Wt[(c0 + j) * 132 + k];
            acc[0][j] = fmaf(a0.x, wv.x, acc[0][j]);
            acc[0][j] = fmaf(a0.y, wv.y, acc[0][j]);
            acc[0][j] = fmaf(a0.z, wv.z, acc[0][j]);
            acc[0][j] = fmaf(a0.w, wv.w, acc[0][j]);
            acc[1][j] = fmaf(a1.x, wv.x, acc[1][j]);
            acc[1][j] = fmaf(a1.y, wv.y, acc[1][j]);
            acc[1][j] = fmaf(a1.z, wv.z, acc[1][j]);
            acc[1][j] = fmaf(a1.w, wv.w, acc[1][j]);
        }
    }
#pragma unroll
    for (int ri = 0; ri < 2; ++ri) {
        int r = base_row + r0 + ri;
        if (r < M) {
            float sc = rs_out[r];
            float v0 = acc[ri][0] * sc, v1 = acc[ri][1] * sc, v2 = acc[ri][2] * sc;
            float v3 = acc[ri][3] * sc, v4 = acc[ri][4] * sc;
            int p0 = __builtin_amdgcn_cvt_pk_fp8_f32(v0, v1, 0, false);
            int p1 = __builtin_amdgcn_cvt_pk_fp8_f32(v2, v3, 0, false);
            int p2 = __builtin_amdgcn_cvt_pk_fp8_f32(v4, v4, 0, false);
            unsigned char* hp = &hs[(r0 + ri) * 40 + c0];
            hp[0] = (unsigned char)(p0 & 0xff);
            hp[1] = (unsigned char)((p0 >> 8) & 0xff);
            hp[2] = (unsigned char)(p1 & 0xff);
            hp[3] = (unsigned char)((p1 >> 8) & 0xff);
            hp[4] = (unsigned char)(p2 & 0xff);
        }
    }
    __syncthreads();
    int vr = min(64, M - base_row);
    int nd = vr * 10;                    // dwords (40 B rows, contiguous)
    const uint32_t* hw = (const uint32_t*)hs;
    for (int idx = t; idx < nd; idx += 256)
        *(uint32_t*)(h2f + (size_t)base_row * 40 + (size_t)idx * 4) = hw[idx];
}

// ---------------- SpMM2 (fp8, MLP) + bias + log_softmax ----------------
// 5 lanes/edge x uint2; 12 edge-groups; f32x2 packed accumulate, mask-free full batches.
__global__ __launch_bounds__(256) void k_spmm2(const unsigned char* __restrict__ h2f, const int* __restrict__ rp,
                                               const int* __restrict__ col, const float* __restrict__ rs_in,
                                               const float* __restrict__ b2, float* __restrict__ out, int n) {
    int w = (blockIdx.x * 256 + threadIdx.x) >> 6;
    int lane = threadIdx.x & 63;
    if (w >= n) return;
    int grp = lane / 5;                  // 0..12 (grp 12 = lanes 60..63; its garbage never reaches the fold)
    int dw = lane - grp * 5;             // 0..4
    bool gval = grp < 12;
    int s = rp[w], e = rp[w + 1];
    f32x2 acc[4] = {};
    int i = s;
    while (i < e) {
        int cnt = min(64, e - i);
        int cl = (lane < cnt) ? lane : cnt - 1;
        int cidx = col[i + cl];
        int it = 0;
        for (; it + 24 <= cnt; it += 24) {       // mask-free (groups 0..11 always in range)
            int cA = __shfl(cidx, (it + grp) & 63, 64);
            int cB = __shfl(cidx, (it + 12 + grp) & 63, 64);
            uint2 uA = *(const uint2*)(h2f + (size_t)cA * 40 + dw * 8);
            uint2 uB = *(const uint2*)(h2f + (size_t)cB * 40 + dw * 8);
            acc[0] += __builtin_amdgcn_cvt_pk_f32_fp8(uA.x, false);
            acc[1] += __builtin_amdgcn_cvt_pk_f32_fp8(uA.x, true);
            acc[2] += __builtin_amdgcn_cvt_pk_f32_fp8(uA.y, false);
            acc[3] += __builtin_amdgcn_cvt_pk_f32_fp8(uA.y, true);
            acc[0] += __builtin_amdgcn_cvt_pk_f32_fp8(uB.x, false);
            acc[1] += __builtin_amdgcn_cvt_pk_f32_fp8(uB.x, true);
            acc[2] += __builtin_amdgcn_cvt_pk_f32_fp8(uB.y, false);
            acc[3] += __builtin_amdgcn_cvt_pk_f32_fp8(uB.y, true);
        }
        if (it < cnt) {                           // masked tail (<=23 edges)
            int eA = it + grp, eB = it + 12 + grp;
            int cA = __shfl(cidx, (eA < cnt) ? eA : 0, 64);
            int cB = __shfl(cidx, (eB < cnt) ? eB : 0, 64);
            float mA = (gval && eA < cnt) ? 1.f : 0.f;
            float mB = (gval && eB < cnt) ? 1.f : 0.f;
            f32x2 vA = {mA, mA}, vB = {mB, mB};
            uint2 uA = *(const uint2*)(h2f + (size_t)cA * 40 + dw * 8);
            uint2 uB = *(const uint2*)(h2f + (size_t)cB * 40 + dw * 8);
            acc[0] += __builtin_amdgcn_cvt_pk_f32_fp8(uA.x, false) * vA;
            acc[1] += __builtin_amdgcn_cvt_pk_f32_fp8(uA.x, true) * vA;
            acc[2] += __builtin_amdgcn_cvt_pk_f32_fp8(uA.y, false) * vA;
            acc[3] += __builtin_amdgcn_cvt_pk_f32_fp8(uA.y, true) * vA;
            acc[0] += __builtin_amdgcn_cvt_pk_f32_fp8(uB.x, false) * vB;
            acc[1] += __builtin_amdgcn_cvt_pk_f32_fp8(uB.x, true) * vB;
            acc[2] += __builtin_amdgcn_cvt_pk_f32_fp8(uB.y, false) * vB;
            acc[3] += __builtin_amdgcn_cvt_pk_f32_fp8(uB.y, true) * vB;
        }
        i += cnt;
    }
    // fold 12 groups (stride 5) -> group 0 (lanes 0..4); lanes 60..63 never feed these paths
#pragma unroll
    for (int j = 0; j < 4; ++j) {
        acc[j].x += __shfl(acc[j].x, (lane + 30) & 63, 64);
        acc[j].y += __shfl(acc[j].y, (lane + 30) & 63, 64);
        acc[j].x += __shfl(acc[j].x, (lane + 15) & 63, 64);
        acc[j].y += __shfl(acc[j].y, (lane + 15) & 63, 64);
        acc[j].x += __shfl(acc[j].x, (lane + 5) & 63, 64) + __shfl(acc[j].x, (lane + 10) & 63, 64);
        acc[j].y += __shfl(acc[j].y, (lane + 5) & 63, 64) + __shfl(acc[j].y, (lane + 10) & 63, 64);
    }
    bool act = lane < 5;
    float sc = rs_in[w];
    float val[8];
#pragma unroll
    for (int j = 0; j < 4; ++j) {
        val[2 * j] = fmaf(acc[j].x, sc, b2[dw * 8 + 2 * j]);
        val[2 * j + 1] = fmaf(acc[j].y, sc, b2[dw * 8 + 2 * j + 1]);
    }
    float pm = -INFINITY;
    if (act) {
        pm = val[0];
#pragma unroll
        for (int j = 1; j < 8; ++j) pm = fmaxf(pm, val[j]);
    }
    pm = fmaxf(pm, __shfl_xor(pm, 4, 8));
    pm = fmaxf(pm, __shfl_xor(pm, 2, 8));
    pm = fmaxf(pm, __shfl_xor(pm, 1, 8));
    float ex = 0.f;
    if (act) {
#pragma unroll
        for (int j = 0; j < 8; ++j) ex += expf(val[j] - pm);
    }
    ex += __shfl_xor(ex, 4, 8);
    ex += __shfl_xor(ex, 2, 8);
    ex += __shfl_xor(ex, 1, 8);
    if (act) {
        float l = pm + logf(ex);
        float4 o0 = {val[0] - l, val[1] - l, val[2] - l, val[3] - l};
        float4 o1 = {val[4] - l, val[5] - l, val[6] - l, val[7] - l};
        float* op = out + (size_t)w * OUT_DIM + dw * 8;
        *(float4*)op = o0;
        *(float4*)(op + 4) = o1;
    }
}

// ---------------- launch ----------------

extern "C" void kernel_launch(void* const* d_in, const int* in_sizes, int n_in,
                              void* d_out, int out_size, void* d_ws, size_t ws_size,
                              hipStream_t stream) {
    const int N = in_sizes[0] / IN_DIM;
    const int E = in_sizes[5];
    const float* h  = (const float*)d_in[0];
    const float* W1 = (const float*)d_in[1];
    const float* b1 = (const float*)d_in[2];
    const float* W2 = (const float*)d_in[3];
    const float* b2 = (const float*)d_in[4];
    const int* src  = (const int*)d_in[5];
    const int* dst  = (const int*)d_in[6];
    float* out = (float*)d_out;

    const int NBINS  = (N + BIN_SIZE - 1) >> BIN_SHIFT;   // 98
    const int NCHUNK = (E + CHUNK - 1) / CHUNK;           // 391

    char* w = (char*)d_ws;
    size_t off = 0;
    auto alloc = [&](size_t bytes) -> void* {
        void* p = w + off;
        off += (bytes + 255) & ~(size_t)255;
        return p;
    };
    int* deg_out  = (int*)alloc((size_t)N * 4);
    int* row_ptr  = (int*)alloc((size_t)(N + 1) * 4);
    int* bsum     = (int*)alloc(1024 * 4);
    float* rs_out = (float*)alloc((size_t)N * 4);
    float* rs_in  = (float*)alloc((size_t)N * 4);
    int* col      = (int*)alloc((size_t)E * 4);
    int* bboD     = (int*)alloc((size_t)NCHUNK * (NBINS + 1) * 4);
    int* pph      = (int*)alloc((size_t)NBINS * GSPLIT * BIN_SIZE * 4);   // 3.2 MB
    int* curg     = (int*)alloc((size_t)NBINS * GSPLIT * BIN_SIZE * 4);   // 3.2 MB
    short* Wg     = (short*)alloc((size_t)8 * 8 * 64 * 8 * 2);            // 64 KB
    uint32_t* h1f = (uint32_t*)alloc((size_t)N * HID);                    // fp8, 12.8 MB
    unsigned char* h2f = (unsigned char*)alloc((size_t)N * OUT_DIM);      // fp8, 4 MB
    uint32_t* x1b = (uint32_t*)alloc((size_t)N * (HID / 2) * 4);          // bf16 permuted, 25.6 MB
    uint32_t* stD = (uint32_t*)x1b;           // staging dead before spmm1 writes x1b (12.8 <= 25.6 MB)

    int gN = (N + 255) / 256;
    int NB = (N + 1023) / 1024;

    hipMemsetAsync(deg_out, 0, (size_t)N * 4, stream);
    k_wrepack<<<32, 256, 0, stream>>>(W1, Wg);
    k_binscatter<<<NCHUNK, 256, 0, stream>>>(src, dst, stD, bboD, deg_out, E, NBINS);
    k_hist<<<dim3(NBINS, GSPLIT), 256, 0, stream>>>(stD, bboD, pph, NCHUNK, NBINS);
    k_scan1<<<NB, 256, 0, stream>>>(pph, row_ptr, bsum, rs_in, N);
    k_scan2<<<1, 1024, 0, stream>>>(bsum, NB);
    k_scan3<<<gN, 256, 0, stream>>>(row_ptr, bsum, pph, curg, deg_out, rs_out, N, E);
    k_col<<<dim3(NBINS, GSPLIT), 256, 0, stream>>>(stD, bboD, curg, col, NCHUNK, NBINS);
    k_gemm1<<<(N + 63) / 64, 256, 0, stream>>>(h, Wg, rs_out, h1f, N);
    k_spmm1<<<(N + 3) / 4, 256, 0, stream>>>((const uint4*)h1f, row_ptr, col, rs_in, b1, x1b, N);
    k_gemm2<<<(N + 63) / 64, 256, 0, stream>>>(x1b, W2, rs_out, h2f, N);
    k_spmm2<<<(N + 3) / 4, 256, 0, stream>>>(h2f, row_ptr, col, rs_in, b2, out, N);
}